// Round 5
// baseline (117.716 us; speedup 1.0000x reference)
//
#include <hip/hip_runtime.h>

// 12-bit ripple-carry adder on {0,1} float spikes == integer add of 12-bit values.
//
// R2: coalesced+LDS, 3 barriers/window -> 122us. R4: barrier-free wave-local
// (ds_bpermute reshuffle) -> 117us, but still only ~3.5 TB/s effective: each
// wave's loads drain fully before its compute phase, so loads-in-flight per CU
// (~2-3 KB) is ~1/3 of the ~9 KB needed to sustain 6.3 TB/s at ~375ns latency.
//
// R5: 1-deep register prefetch — issue window w+1's 6 loads BEFORE computing
// window w. vmcnt wait for w+1 lands at next iteration's pack, so loads stay
// in flight across the whole bperm/store phase. +24 VGPR, target <=64 total.

typedef float f32x4 __attribute__((ext_vector_type(4)));
typedef unsigned u32x4 __attribute__((ext_vector_type(4)));

struct Win { u32x4 a0, a1, a2, b0, b1, b2; };

__device__ __forceinline__ unsigned bperm(unsigned src, int srclane) {
    return (unsigned)__builtin_amdgcn_ds_bpermute(srclane << 2, (int)src);
}

// bit (0 or 1) -> 0.0f / 1.0f without cvt: mask-select the full 1.0f pattern
__device__ __forceinline__ float bit2f(unsigned bit) {
    return __uint_as_float(0x3F800000u & (0u - bit));
}

// float4 of {0,1} spikes -> 4-bit nibble (x = MSB). 1.0f = 0x3F800000, bit 23.
__device__ __forceinline__ unsigned nib(u32x4 u) {
    return ((u.x >> 20) & 8u) | ((u.y >> 21) & 4u) |
           ((u.z >> 22) & 2u) | ((u.w >> 23) & 1u);
}

__global__ __launch_bounds__(256) void adder12_pf_kernel(
    const float* __restrict__ A, const float* __restrict__ B,
    float* __restrict__ sums, float* __restrict__ carry, int nrows) {
    const int lane = threadIdx.x & 63;
    const int waveRow = threadIdx.x & 192;  // wave's 64-row slice of the 256-row window
    const int nwin = nrows >> 8;

    auto loadw = [&](int w) {
        Win r;
        const size_t fbase = (((size_t)w << 8) + waveRow) * 12;
        const u32x4* a4 = reinterpret_cast<const u32x4*>(A + fbase) + lane;
        const u32x4* b4 = reinterpret_cast<const u32x4*>(B + fbase) + lane;
        r.a0 = a4[0]; r.a1 = a4[64]; r.a2 = a4[128];
        r.b0 = b4[0]; r.b1 = b4[64]; r.b2 = b4[128];
        return r;
    };

    Win cur = loadw(blockIdx.x);  // prologue
    for (int w = blockIdx.x; w < nwin; w += gridDim.x) {
        const int wn = w + gridDim.x;
        Win nxt;
        if (wn < nwin) nxt = loadw(wn);  // prefetch: in flight across this window's compute

        // --- pack each quad to a nibble; bits [4k+3:4k] = quad (lane + 64k) ---
        const unsigned packedA = nib(cur.a0) | (nib(cur.a1) << 4) | (nib(cur.a2) << 8);
        const unsigned packedB = nib(cur.b0) | (nib(cur.b1) << 4) | (nib(cur.b2) << 8);

        // --- gather my row's 3 nibbles (MSB quad first) via ds_bpermute ---
        unsigned ra = 0, rb = 0;
#pragma unroll
        for (int j = 0; j < 3; ++j) {
            const int q = 3 * lane + j;          // quad index in wave window (0..191)
            const unsigned va = bperm(packedA, q & 63);
            const unsigned vb = bperm(packedB, q & 63);
            const int sh = 4 * (q >> 6);         // nibble slot in the source lane
            ra = (ra << 4) | ((va >> sh) & 0xFu);
            rb = (rb << 4) | ((vb >> sh) & 0xFu);
        }
        const unsigned s = ra + rb;  // 13-bit sum for row (rowbase + lane)

        const size_t rowbase = ((size_t)w << 8) + waveRow;
        __builtin_nontemporal_store(bit2f(s >> 12), carry + rowbase + lane);

        // --- emit: lane stores 3 coalesced quads; quad p lies wholly in row p/3 ---
        f32x4* o4 = reinterpret_cast<f32x4*>(sums + rowbase * 12);
#pragma unroll
        for (int k = 0; k < 3; ++k) {
            const int p = lane + (k << 6);
            const int r = p / 3;
            const int m = p - 3 * r;
            const unsigned sv = bperm(s, r);
            const int b0 = 11 - (m << 2);        // bit index of quad's first float
            f32x4 ov;
            ov.x = bit2f((sv >> b0) & 1u);
            ov.y = bit2f((sv >> (b0 - 1)) & 1u);
            ov.z = bit2f((sv >> (b0 - 2)) & 1u);
            ov.w = bit2f((sv >> (b0 - 3)) & 1u);
            __builtin_nontemporal_store(ov, o4 + p);
        }

        cur = nxt;  // dead copy on final iteration (nxt unloaded) — loop exits
    }
}

extern "C" void kernel_launch(void* const* d_in, const int* in_sizes, int n_in,
                              void* d_out, int out_size, void* d_ws, size_t ws_size,
                              hipStream_t stream) {
    const float* A = (const float*)d_in[0];
    const float* B = (const float*)d_in[1];
    const int n = in_sizes[0] / 12;  // rows (4194304)
    float* sums = (float*)d_out;                 // [n,12] flat
    float* carry = sums + (size_t)n * 12;        // [n,1]

    const int block = 256;
    const int nwin = n >> 8;                     // 16384 windows of 256 rows
    int grid = nwin < 2048 ? nwin : 2048;        // grid-stride over windows
    adder12_pf_kernel<<<grid, block, 0, stream>>>(A, B, sums, carry, n);
}

// Round 6
// 115.287 us; speedup vs baseline: 1.0211x; 1.0211x over previous
//
#include <hip/hip_runtime.h>

// 12-bit ripple-carry adder on {0,1} float spikes == integer add of 12-bit values.
//
// History: R1 row-per-thread strided 127us; R2 LDS+3 barriers 122us; R4 wave-local
// bperm + nontemporal stores 117us; R5 register prefetch NO-OP (compiler sank the
// guarded loads; VGPR 44 not 56+). All structures pinned ~117-127us with VALUBusy
// ~8% and HBM ~55% => waves stall on memory counters, not issue/volume/latency.
//
// R6 theory: `nt` stores bypass L2/L3 -> 218 MB write stream hits HBM write queues
// raw; backpressure holds store data in VGPRs -> long vmcnt waits before register
// reuse, identical in every structure. Fix: REGULAR stores (L3 absorbs/smooths
// write bursts) + one window per block (16384 blocks, no loop -> block turnover
// provides the pipelining R5 couldn't).

typedef float f32x4 __attribute__((ext_vector_type(4)));
typedef unsigned u32x4 __attribute__((ext_vector_type(4)));

__device__ __forceinline__ unsigned bperm(unsigned src, int srclane) {
    return (unsigned)__builtin_amdgcn_ds_bpermute(srclane << 2, (int)src);
}

// bit (0 or 1) -> 0.0f / 1.0f without cvt: mask-select the full 1.0f pattern
__device__ __forceinline__ float bit2f(unsigned bit) {
    return __uint_as_float(0x3F800000u & (0u - bit));
}

// float4 of {0,1} spikes -> 4-bit nibble (x = MSB). 1.0f = 0x3F800000, bit 23.
__device__ __forceinline__ unsigned nib(u32x4 u) {
    return ((u.x >> 20) & 8u) | ((u.y >> 21) & 4u) |
           ((u.z >> 22) & 2u) | ((u.w >> 23) & 1u);
}

__global__ __launch_bounds__(256) void adder12_block_kernel(
    const float* __restrict__ A, const float* __restrict__ B,
    float* __restrict__ sums, float* __restrict__ carry) {
    const int lane = threadIdx.x & 63;
    const int waveRow = threadIdx.x & 192;  // wave's 64-row slice of this block's 256 rows

    const size_t rowbase = ((size_t)blockIdx.x << 8) + waveRow;  // first row this wave owns
    const size_t fbase = rowbase * 12;                           // flat float index
    const u32x4* a4 = reinterpret_cast<const u32x4*>(A + fbase) + lane;
    const u32x4* b4 = reinterpret_cast<const u32x4*>(B + fbase) + lane;

    // --- coalesced loads; pack each float4 into a 4-bit nibble ---
    // bits [4k+3:4k] of packed = nibble of quad (lane + 64k)
    const u32x4 ua0 = a4[0], ua1 = a4[64], ua2 = a4[128];
    const u32x4 ub0 = b4[0], ub1 = b4[64], ub2 = b4[128];
    const unsigned packedA = nib(ua0) | (nib(ua1) << 4) | (nib(ua2) << 8);
    const unsigned packedB = nib(ub0) | (nib(ub1) << 4) | (nib(ub2) << 8);

    // --- gather my row's 3 nibbles (MSB quad first) via ds_bpermute ---
    unsigned ra = 0, rb = 0;
#pragma unroll
    for (int j = 0; j < 3; ++j) {
        const int q = 3 * lane + j;          // quad index in wave window (0..191)
        const unsigned va = bperm(packedA, q & 63);
        const unsigned vb = bperm(packedB, q & 63);
        const int sh = 4 * (q >> 6);         // nibble slot in the source lane
        ra = (ra << 4) | ((va >> sh) & 0xFu);
        rb = (rb << 4) | ((vb >> sh) & 0xFu);
    }
    const unsigned s = ra + rb;  // 13-bit sum for row (rowbase + lane)

    carry[rowbase + lane] = bit2f(s >> 12);  // coalesced b32 store

    // --- emit: lane stores 3 coalesced quads; quad p lies wholly in row p/3 ---
    f32x4* o4 = reinterpret_cast<f32x4*>(sums + fbase);
#pragma unroll
    for (int k = 0; k < 3; ++k) {
        const int p = lane + (k << 6);
        const int r = p / 3;
        const int m = p - 3 * r;
        const unsigned sv = bperm(s, r);
        const int b0 = 11 - (m << 2);        // bit index of quad's first float
        f32x4 ov;
        ov.x = bit2f((sv >> b0) & 1u);
        ov.y = bit2f((sv >> (b0 - 1)) & 1u);
        ov.z = bit2f((sv >> (b0 - 2)) & 1u);
        ov.w = bit2f((sv >> (b0 - 3)) & 1u);
        o4[p] = ov;
    }
}

extern "C" void kernel_launch(void* const* d_in, const int* in_sizes, int n_in,
                              void* d_out, int out_size, void* d_ws, size_t ws_size,
                              hipStream_t stream) {
    const float* A = (const float*)d_in[0];
    const float* B = (const float*)d_in[1];
    const int n = in_sizes[0] / 12;  // rows (4194304)
    float* sums = (float*)d_out;                 // [n,12] flat
    float* carry = sums + (size_t)n * 12;        // [n,1]

    const int block = 256;
    const int grid = n >> 8;                     // 16384 blocks, one 256-row window each
    adder12_block_kernel<<<grid, block, 0, stream>>>(A, B, sums, carry);
}